// Round 2
// baseline (9801.999 us; speedup 1.0000x reference)
//
#include <hip/hip_runtime.h>
#include <hip/hip_fp16.h>
#include <cstdint>
#include <cstddef>

#define BB 64      // batch
#define TT 2048    // time
#define DD 256     // input dim
#define HH 256     // hidden
#define G4 1024    // 4*H

typedef unsigned int u32;

// ---------------- activation helpers (fp32) ----------------
__device__ __forceinline__ float sigf(float x) {
    return 1.0f / (1.0f + __expf(-x));
}
__device__ __forceinline__ float tanhfast(float x) {
    float ax = fabsf(x);
    float t  = __expf(-2.0f * ax);
    float r  = (1.0f - t) / (1.0f + t);
    return copysignf(r, x);
}

// ---------------- f16 dot2 ----------------
#if defined(__has_builtin)
#if __has_builtin(__builtin_amdgcn_fdot2)
#define HAVE_FDOT2 1
#endif
#endif

typedef _Float16 f16x2 __attribute__((ext_vector_type(2)));

__device__ __forceinline__ float dot2f(u32 a, u32 b, float c) {
#ifdef HAVE_FDOT2
    return __builtin_amdgcn_fdot2(__builtin_bit_cast(f16x2, a),
                                  __builtin_bit_cast(f16x2, b), c, false);
#else
    __half2 ah = *reinterpret_cast<__half2*>(&a);
    __half2 bh = *reinterpret_cast<__half2*>(&b);
    float2 af = __half22float2(ah), bf = __half22float2(bh);
    return c + af.x * bf.x + af.y * bf.y;
#endif
}

// ---------------- prep: pack W_h (rows D..D+H) into f16 pairs along k ----------------
// whp[k2][c] = half2( W[D+2k2][c], W[D+2k2+1][c] ),  k2 in [0,128), c in [0,1024)
__global__ __launch_bounds__(256) void prep_wh(const float* __restrict__ W, u32* __restrict__ whp) {
    int idx = blockIdx.x * 256 + threadIdx.x;   // < 131072
    int k2 = idx >> 10, c = idx & 1023;
    float lo = W[(size_t)(DD + 2 * k2) * G4 + c];
    float hi = W[(size_t)(DD + 2 * k2 + 1) * G4 + c];
    __half2 h = __floats2half2_rn(lo, hi);
    whp[idx] = *reinterpret_cast<u32*>(&h);
}

// ---------------- init state c,h = 0 ----------------
__global__ __launch_bounds__(256) void init_state(float* __restrict__ cst, float* __restrict__ hst) {
    int i = blockIdx.x * 256 + threadIdx.x;     // < 16384
    cst[i] = 0.0f;
    hst[i] = 0.0f;
}

// ---------------- GEMM: xw[m][n] = bias[n] + sum_k x_row(m)[k] * W[k][n]  (k<D) ----------------
#define BM 128
#define BN 64
#define BK 32

__global__ __launch_bounds__(256) void gemm_xw(const float* __restrict__ x,
                                               const float* __restrict__ W,
                                               const float* __restrict__ bias,
                                               const int* __restrict__ seqlen,
                                               float* __restrict__ xw,
                                               int t0, int ct) {
    const int m0 = blockIdx.x * BM;
    const int b  = m0 / ct;
    const int tl0 = m0 - b * ct;
    if (t0 + tl0 >= seqlen[b]) return;          // whole tile past this batch's length
    const int n0 = blockIdx.y * BN;

    __shared__ __align__(16) float xs[BK][BM + 4];
    __shared__ __align__(16) float wsm[BK][BN];

    const int tid = threadIdx.x;
    const int tx = tid & 15, ty = tid >> 4;
    const float* xrowbase = x + ((size_t)b * TT + t0 + tl0) * DD;

    float4 acc[8];
    #pragma unroll
    for (int i = 0; i < 8; ++i) acc[i] = make_float4(0.f, 0.f, 0.f, 0.f);

    for (int k0 = 0; k0 < DD; k0 += BK) {
        #pragma unroll
        for (int i = 0; i < 4; ++i) {
            int idx = tid + i * 256;            // 0..1023
            int r = idx >> 3, kv = idx & 7;
            float4 v = *reinterpret_cast<const float4*>(xrowbase + (size_t)r * DD + k0 + kv * 4);
            xs[kv * 4 + 0][r] = v.x; xs[kv * 4 + 1][r] = v.y;
            xs[kv * 4 + 2][r] = v.z; xs[kv * 4 + 3][r] = v.w;
        }
        #pragma unroll
        for (int i = 0; i < 2; ++i) {
            int idx = tid + i * 256;            // 0..511
            int kr = idx >> 4, cv = idx & 15;
            *reinterpret_cast<float4*>(&wsm[kr][cv * 4]) =
                *reinterpret_cast<const float4*>(W + (size_t)(k0 + kr) * G4 + n0 + cv * 4);
        }
        __syncthreads();
        #pragma unroll
        for (int k = 0; k < BK; ++k) {
            float4 a0 = *reinterpret_cast<const float4*>(&xs[k][ty * 8]);
            float4 a1 = *reinterpret_cast<const float4*>(&xs[k][ty * 8 + 4]);
            float4 bv = *reinterpret_cast<const float4*>(&wsm[k][tx * 4]);
            float ai[8] = {a0.x, a0.y, a0.z, a0.w, a1.x, a1.y, a1.z, a1.w};
            #pragma unroll
            for (int i = 0; i < 8; ++i) {
                acc[i].x += ai[i] * bv.x; acc[i].y += ai[i] * bv.y;
                acc[i].z += ai[i] * bv.z; acc[i].w += ai[i] * bv.w;
            }
        }
        __syncthreads();
    }
    float4 bv = *reinterpret_cast<const float4*>(bias + n0 + tx * 4);
    float* outbase = xw + (size_t)m0 * G4 + n0 + tx * 4;
    #pragma unroll
    for (int i = 0; i < 8; ++i) {
        float4 o = make_float4(acc[i].x + bv.x, acc[i].y + bv.y,
                               acc[i].z + bv.z, acc[i].w + bv.w);
        *reinterpret_cast<float4*>(outbase + (size_t)(ty * 8 + i) * G4) = o;
    }
}

// ---------------- recurrent LSTM chunk ----------------
// 64 blocks (one per batch element) x 512 threads (8 waves).
// Lane mapping (within wave w, lane l):
//   gate g = (l>>4)&3   (0=i, 1=j, 2=f, 3=o — TF order)
//   col pair p = (l&15) + 16*w   (p in [0,128): h columns 2p, 2p+1)
//   thread computes gate g for cols 2p,2p+1 -> flat gate cols n0=256g+2p, n0+1.
// All of W_h (f16-pair packed, 256 u32/thread) lives in registers (VGPR+AGPR).
// h double-buffered in LDS (2 x 512B). ONE barrier per step. Gates of a column
// are exchanged in-wave via __shfl_xor(16/32/48); lanes l<16 do the activation.
#define NT 512
#define KREG 128   // all 128 k2 pairs in registers

__global__ __launch_bounds__(NT, 1) void lstm_chunk(const u32* __restrict__ whp,
                                                    const float* __restrict__ xw,
                                                    const int* __restrict__ seqlen,
                                                    float* __restrict__ y,
                                                    float* __restrict__ cst,
                                                    float* __restrict__ hst,
                                                    int t0, int ct) {
    __shared__ __align__(16) u32 hbuf[2][128];   // 2 x 256 f16 (pair-packed)

    const int tid = threadIdx.x;
    const int b   = blockIdx.x;
    const int slen = seqlen[b];
    const int w = tid >> 6;
    const int l = tid & 63;
    const int g = (l >> 4) & 3;
    const int p = (l & 15) + 16 * w;
    const int n0 = 256 * g + 2 * p;

    // --- W_h register load: wr[k2] = { wpair[k2][n0], wpair[k2][n0+1] } ---
    uint2 wr[KREG];
    #pragma unroll
    for (int i = 0; i < KREG; ++i)
        wr[i] = *reinterpret_cast<const uint2*>(whp + (size_t)i * 1024 + n0);

    // --- state load; lanes l<16 own c for cols 2p,2p+1 and seed hbuf[0] ---
    const bool actlane = (l < 16);
    float2 c01 = make_float2(0.f, 0.f);
    if (actlane) {
        c01 = *reinterpret_cast<const float2*>(cst + b * HH + 2 * p);
        float2 h01 = *reinterpret_cast<const float2*>(hst + b * HH + 2 * p);
        __half2 hp = __floats2half2_rn(h01.x, h01.y);
        hbuf[0][p] = *reinterpret_cast<u32*>(&hp);
    }
    __syncthreads();

    const float* xwbase = xw + ((size_t)b * ct) * G4 + n0;
    float2 xwc = *reinterpret_cast<const float2*>(xwbase);
    int pp = 0;

    int tl = 0;
    for (; tl < ct; ++tl) {
        if (t0 + tl >= slen) break;

        // prefetch next timestep's xw row (value discarded if past slen)
        float2 xwn = xwc;
        if (tl + 1 < ct)
            xwn = *reinterpret_cast<const float2*>(xwbase + (size_t)(tl + 1) * G4);

        float a0 = xwc.x, a1 = xwc.y;
        float e0 = 0.f, e1 = 0.f;   // second accumulator pair (shorter dep chains)

        const uint4* h4 = reinterpret_cast<const uint4*>(hbuf[pp]);
        #pragma unroll
        for (int kb = 0; kb < 32; ++kb) {
            uint4 hh = h4[kb];                 // broadcast: 8 h values (4 k2 pairs)
            a0 = dot2f(hh.x, wr[4 * kb + 0].x, a0); a1 = dot2f(hh.x, wr[4 * kb + 0].y, a1);
            e0 = dot2f(hh.y, wr[4 * kb + 1].x, e0); e1 = dot2f(hh.y, wr[4 * kb + 1].y, e1);
            a0 = dot2f(hh.z, wr[4 * kb + 2].x, a0); a1 = dot2f(hh.z, wr[4 * kb + 2].y, a1);
            e0 = dot2f(hh.w, wr[4 * kb + 3].x, e0); e1 = dot2f(hh.w, wr[4 * kb + 3].y, e1);
        }
        a0 += e0; a1 += e1;

        // in-wave gate exchange: partner lanes l^16 (j), l^32 (f), l^48 (o)
        float j0 = __shfl_xor(a0, 16), j1 = __shfl_xor(a1, 16);
        float f0 = __shfl_xor(a0, 32), f1 = __shfl_xor(a1, 32);
        float o0 = __shfl_xor(a0, 48), o1 = __shfl_xor(a1, 48);

        if (actlane) {                          // lanes with g==0: own a = i-gates
            float nc0 = c01.x * sigf(f0 + 1.0f) + sigf(a0) * tanhfast(j0);
            float nc1 = c01.y * sigf(f1 + 1.0f) + sigf(a1) * tanhfast(j1);
            float nh0 = tanhfast(nc0) * sigf(o0);
            float nh1 = tanhfast(nc1) * sigf(o1);
            c01 = make_float2(nc0, nc1);
            __half2 hp = __floats2half2_rn(nh0, nh1);
            hbuf[pp ^ 1][p] = *reinterpret_cast<u32*>(&hp);
            *reinterpret_cast<float2*>(y + ((size_t)b * TT + t0 + tl) * HH + 2 * p) =
                make_float2(nh0, nh1);
        }
        __syncthreads();
        pp ^= 1;
        xwc = xwn;
    }

    // zero-fill masked tail of this chunk (reference outputs 0 past seq_len)
    if (tl < ct) {
        float4 z = make_float4(0.f, 0.f, 0.f, 0.f);
        size_t base = ((size_t)b * TT + t0 + tl) * HH;
        size_t total = (size_t)(ct - tl) * HH;
        for (size_t i = 4 * (size_t)tid; i < total; i += 4 * NT)
            *reinterpret_cast<float4*>(y + base + i) = z;
    }

    // persist state for next chunk
    if (actlane) {
        *reinterpret_cast<float2*>(cst + b * HH + 2 * p) = c01;
        u32 hu = hbuf[pp][p];
        __half2 hp = *reinterpret_cast<__half2*>(&hu);
        float2 hf = __half22float2(hp);
        *reinterpret_cast<float2*>(hst + b * HH + 2 * p) = hf;
    }
}

// ---------------- host ----------------
extern "C" void kernel_launch(void* const* d_in, const int* in_sizes, int n_in,
                              void* d_out, int out_size, void* d_ws, size_t ws_size,
                              hipStream_t stream) {
    (void)in_sizes; (void)n_in; (void)out_size;
    const float* x      = (const float*)d_in[0];
    const float* W      = (const float*)d_in[1];
    const float* bias   = (const float*)d_in[2];
    const int*   seqlen = (const int*)d_in[3];
    float* y = (float*)d_out;

    // workspace layout: [whp 512KB][c 64KB][h 64KB][xw chunk buffer ...]
    u32*   whp = (u32*)d_ws;
    float* cst = (float*)((char*)d_ws + (512 << 10));
    float* hst = cst + BB * HH;
    float* xwbuf = (float*)((char*)d_ws + (640 << 10));

    long long avail = (long long)ws_size - (640 << 10);
    int ctu = 128;
    if (avail > 0) {
        long long mx = avail / ((long long)BB * G4 * 4);  // 256KB per timestep
        int mm = (int)((mx / 128) * 128);
        if (mm >= 128) ctu = mm;
    }
    if (ctu > TT) ctu = TT;

    prep_wh<<<dim3(512), 256, 0, stream>>>(W, whp);
    init_state<<<dim3(64), 256, 0, stream>>>(cst, hst);

    int done = 0;
    while (done < TT) {
        int ct = ctu;
        if (ct > TT - done) ct = TT - done;
        gemm_xw<<<dim3((BB * ct) / BM, G4 / BN), 256, 0, stream>>>(x, W, bias, seqlen, xwbuf, done, ct);
        lstm_chunk<<<dim3(BB), NT, 0, stream>>>(whp, xwbuf, seqlen, y, cst, hst, done, ct);
        done += ct;
    }
}

// Round 3
// 5879.986 us; speedup vs baseline: 1.6670x; 1.6670x over previous
//
#include <hip/hip_runtime.h>
#include <hip/hip_fp16.h>
#include <cstdint>
#include <cstddef>

#define BB 64      // batch
#define TT 2048    // time
#define DD 256     // input dim
#define HH 256     // hidden
#define G4 1024    // 4*H

typedef unsigned int u32;

// ---------------- activation helpers (fp32) ----------------
__device__ __forceinline__ float sigf(float x) {
    return 1.0f / (1.0f + __expf(-x));
}
__device__ __forceinline__ float tanhfast(float x) {
    float ax = fabsf(x);
    float t  = __expf(-2.0f * ax);
    float r  = (1.0f - t) / (1.0f + t);
    return copysignf(r, x);
}

// ---------------- f16 dot2 ----------------
#if defined(__has_builtin)
#if __has_builtin(__builtin_amdgcn_fdot2)
#define HAVE_FDOT2 1
#endif
#endif

typedef _Float16 f16x2 __attribute__((ext_vector_type(2)));

__device__ __forceinline__ float dot2f(u32 a, u32 b, float c) {
#ifdef HAVE_FDOT2
    return __builtin_amdgcn_fdot2(__builtin_bit_cast(f16x2, a),
                                  __builtin_bit_cast(f16x2, b), c, false);
#else
    __half2 ah = *reinterpret_cast<__half2*>(&a);
    __half2 bh = *reinterpret_cast<__half2*>(&b);
    float2 af = __half22float2(ah), bf = __half22float2(bh);
    return c + af.x * bf.x + af.y * bf.y;
#endif
}

__device__ __forceinline__ u32 rdlane(u32 v, int lane) {
    return (u32)__builtin_amdgcn_readlane((int)v, lane);
}

// ---------------- prep: pack W_h (rows D..D+H) into f16 pairs along k ----------------
// whp[k2][c] = half2( W[D+2k2][c], W[D+2k2+1][c] ),  k2 in [0,128), c in [0,1024)
__global__ __launch_bounds__(256) void prep_wh(const float* __restrict__ W, u32* __restrict__ whp) {
    int idx = blockIdx.x * 256 + threadIdx.x;   // < 131072
    int k2 = idx >> 10, c = idx & 1023;
    float lo = W[(size_t)(DD + 2 * k2) * G4 + c];
    float hi = W[(size_t)(DD + 2 * k2 + 1) * G4 + c];
    __half2 h = __floats2half2_rn(lo, hi);
    whp[idx] = *reinterpret_cast<u32*>(&h);
}

// ---------------- init state c,h = 0 ----------------
__global__ __launch_bounds__(256) void init_state(float* __restrict__ cst, float* __restrict__ hst) {
    int i = blockIdx.x * 256 + threadIdx.x;     // < 16384
    cst[i] = 0.0f;
    hst[i] = 0.0f;
}

// ---------------- GEMM: xw[m][n] = bias[n] + sum_k x_row(m)[k] * W[k][n]  (k<D) ----------------
#define BM 128
#define BN 64
#define BK 32

__global__ __launch_bounds__(256) void gemm_xw(const float* __restrict__ x,
                                               const float* __restrict__ W,
                                               const float* __restrict__ bias,
                                               const int* __restrict__ seqlen,
                                               float* __restrict__ xw,
                                               int t0, int ct) {
    const int m0 = blockIdx.x * BM;
    const int b  = m0 / ct;
    const int tl0 = m0 - b * ct;
    if (t0 + tl0 >= seqlen[b]) return;          // whole tile past this batch's length
    const int n0 = blockIdx.y * BN;

    __shared__ __align__(16) float xs[BK][BM + 4];
    __shared__ __align__(16) float wsm[BK][BN];

    const int tid = threadIdx.x;
    const int tx = tid & 15, ty = tid >> 4;
    const float* xrowbase = x + ((size_t)b * TT + t0 + tl0) * DD;

    float4 acc[8];
    #pragma unroll
    for (int i = 0; i < 8; ++i) acc[i] = make_float4(0.f, 0.f, 0.f, 0.f);

    for (int k0 = 0; k0 < DD; k0 += BK) {
        #pragma unroll
        for (int i = 0; i < 4; ++i) {
            int idx = tid + i * 256;            // 0..1023
            int r = idx >> 3, kv = idx & 7;
            float4 v = *reinterpret_cast<const float4*>(xrowbase + (size_t)r * DD + k0 + kv * 4);
            xs[kv * 4 + 0][r] = v.x; xs[kv * 4 + 1][r] = v.y;
            xs[kv * 4 + 2][r] = v.z; xs[kv * 4 + 3][r] = v.w;
        }
        #pragma unroll
        for (int i = 0; i < 2; ++i) {
            int idx = tid + i * 256;            // 0..511
            int kr = idx >> 4, cv = idx & 15;
            *reinterpret_cast<float4*>(&wsm[kr][cv * 4]) =
                *reinterpret_cast<const float4*>(W + (size_t)(k0 + kr) * G4 + n0 + cv * 4);
        }
        __syncthreads();
        #pragma unroll
        for (int k = 0; k < BK; ++k) {
            float4 a0 = *reinterpret_cast<const float4*>(&xs[k][ty * 8]);
            float4 a1 = *reinterpret_cast<const float4*>(&xs[k][ty * 8 + 4]);
            float4 bv = *reinterpret_cast<const float4*>(&wsm[k][tx * 4]);
            float ai[8] = {a0.x, a0.y, a0.z, a0.w, a1.x, a1.y, a1.z, a1.w};
            #pragma unroll
            for (int i = 0; i < 8; ++i) {
                acc[i].x += ai[i] * bv.x; acc[i].y += ai[i] * bv.y;
                acc[i].z += ai[i] * bv.z; acc[i].w += ai[i] * bv.w;
            }
        }
        __syncthreads();
    }
    float4 bv = *reinterpret_cast<const float4*>(bias + n0 + tx * 4);
    float* outbase = xw + (size_t)m0 * G4 + n0 + tx * 4;
    #pragma unroll
    for (int i = 0; i < 8; ++i) {
        float4 o = make_float4(acc[i].x + bv.x, acc[i].y + bv.y,
                               acc[i].z + bv.z, acc[i].w + bv.w);
        *reinterpret_cast<float4*>(outbase + (size_t)(ty * 8 + i) * G4) = o;
    }
}

// ---------------- recurrent LSTM chunk ----------------
// 64 blocks (one per batch element) x 512 threads (8 waves, 2 waves/SIMD).
// Lane mapping (wave w, lane l):
//   gate g = (l>>4)&3   (0=i, 1=j, 2=f, 3=o — TF order)
//   col pair p = (l&15) + 16*w   (p in [0,128): h columns 2p, 2p+1)
//   thread computes gate g for cols 2p,2p+1 -> flat gate cols n0=256g+2p, n0+1.
// W_h f16-pair packed: k2 in [0,96) in registers (192 VGPRs, fits 2x~230<=512
// pool regs/SIMD), k2 in [96,128) streamed from LDS each step.
// h delivery: ds_read_b64 (8B/lane) + v_readlane -> SGPR broadcast into
// v_dot2 src0 — replaces ~3000 cyc/step of LDS broadcast-return bandwidth.
// ONE barrier per step; gate exchange via in-wave __shfl_xor(16/32/48).
#define NT 512
#define KREG 96   // k2 pairs in registers (proven no-spill)
#define KLDS 32   // k2 pairs streamed from LDS

__global__ __launch_bounds__(NT, 2) void lstm_chunk(const u32* __restrict__ whp,
                                                    const float* __restrict__ xw,
                                                    const int* __restrict__ seqlen,
                                                    float* __restrict__ y,
                                                    float* __restrict__ cst,
                                                    float* __restrict__ hst,
                                                    int t0, int ct) {
    __shared__ __align__(16) u32 w2lds[KLDS * 1024];   // 128 KB
    __shared__ __align__(16) u32 hbuf[2][128];         // 2 x 256 f16 (pair-packed)

    const int tid = threadIdx.x;
    const int b   = blockIdx.x;
    const int slen = seqlen[b];
    const int w = tid >> 6;
    const int l = tid & 63;
    const int g = (l >> 4) & 3;
    const int p = (l & 15) + 16 * w;
    const int n0 = 256 * g + 2 * p;

    // --- W_h register part: wr[k2] = { wpair[k2][n0], wpair[k2][n0+1] } ---
    uint2 wr[KREG];
    #pragma unroll
    for (int i = 0; i < KREG; ++i)
        wr[i] = *reinterpret_cast<const uint2*>(whp + (size_t)i * 1024 + n0);

    // --- stage LDS part of W_h: rows k2 = KREG..127 ---
    {
        const uint4* src = reinterpret_cast<const uint4*>(whp + KREG * 1024);
        uint4* dst = reinterpret_cast<uint4*>(w2lds);
        for (int i = tid; i < (KLDS * 1024) / 4; i += NT) dst[i] = src[i];
    }

    // --- state load; lanes l<16 own c for cols 2p,2p+1 and seed hbuf[0] ---
    const bool actlane = (l < 16);
    float2 c01 = make_float2(0.f, 0.f);
    if (actlane) {
        c01 = *reinterpret_cast<const float2*>(cst + b * HH + 2 * p);
        float2 h01 = *reinterpret_cast<const float2*>(hst + b * HH + 2 * p);
        __half2 hp = __floats2half2_rn(h01.x, h01.y);
        hbuf[0][p] = *reinterpret_cast<u32*>(&hp);
    }
    __syncthreads();

    const float* xwbase = xw + ((size_t)b * ct) * G4 + n0;
    float2 xwc = *reinterpret_cast<const float2*>(xwbase);
    int pp = 0;

    int tl = 0;
    for (; tl < ct; ++tl) {
        if (t0 + tl >= slen) break;

        // unconditional prefetch of next step's xw row (clamped; issued early)
        int nx = (tl + 1 < ct) ? (tl + 1) : tl;
        float2 xwn = *reinterpret_cast<const float2*>(xwbase + (size_t)nx * G4);

        // lane reads its 2 h pairs: pair[2l] and pair[2l+1]
        uint2 vh = *reinterpret_cast<const uint2*>(&hbuf[pp][2 * l]);

        float a0 = xwc.x, a1 = xwc.y;
        float e0 = 0.f, e1 = 0.f;

        // register part: k2 in [0,KREG) — h pair via readlane->SGPR broadcast
        #pragma unroll
        for (int k2 = 0; k2 < KREG; k2 += 2) {
            u32 h0 = rdlane(vh.x, k2 >> 1);
            a0 = dot2f(h0, wr[k2].x, a0);
            a1 = dot2f(h0, wr[k2].y, a1);
            u32 h1 = rdlane(vh.y, k2 >> 1);
            e0 = dot2f(h1, wr[k2 + 1].x, e0);
            e1 = dot2f(h1, wr[k2 + 1].y, e1);
        }
        // LDS part: k2 in [KREG,128)
        #pragma unroll
        for (int r = 0; r < KLDS; r += 2) {
            int k2 = KREG + r;
            u32 h0 = rdlane(vh.x, k2 >> 1);
            uint2 wl0 = *reinterpret_cast<const uint2*>(&w2lds[(size_t)r * 1024 + n0]);
            a0 = dot2f(h0, wl0.x, a0);
            a1 = dot2f(h0, wl0.y, a1);
            u32 h1 = rdlane(vh.y, k2 >> 1);
            uint2 wl1 = *reinterpret_cast<const uint2*>(&w2lds[(size_t)(r + 1) * 1024 + n0]);
            e0 = dot2f(h1, wl1.x, e0);
            e1 = dot2f(h1, wl1.y, e1);
        }
        a0 += e0; a1 += e1;

        // in-wave gate exchange: partner lanes l^16 (j), l^32 (f), l^48 (o)
        float j0 = __shfl_xor(a0, 16), j1 = __shfl_xor(a1, 16);
        float f0 = __shfl_xor(a0, 32), f1 = __shfl_xor(a1, 32);
        float o0 = __shfl_xor(a0, 48), o1 = __shfl_xor(a1, 48);

        if (actlane) {                          // lanes with g==0: own a = i-gates
            float nc0 = c01.x * sigf(f0 + 1.0f) + sigf(a0) * tanhfast(j0);
            float nc1 = c01.y * sigf(f1 + 1.0f) + sigf(a1) * tanhfast(j1);
            float nh0 = tanhfast(nc0) * sigf(o0);
            float nh1 = tanhfast(nc1) * sigf(o1);
            c01 = make_float2(nc0, nc1);
            __half2 hp = __floats2half2_rn(nh0, nh1);
            hbuf[pp ^ 1][p] = *reinterpret_cast<u32*>(&hp);
            *reinterpret_cast<float2*>(y + ((size_t)b * TT + t0 + tl) * HH + 2 * p) =
                make_float2(nh0, nh1);
        }
        __syncthreads();
        pp ^= 1;
        xwc = xwn;
    }

    // zero-fill masked tail of this chunk (reference outputs 0 past seq_len)
    if (tl < ct) {
        float4 z = make_float4(0.f, 0.f, 0.f, 0.f);
        size_t base = ((size_t)b * TT + t0 + tl) * HH;
        size_t total = (size_t)(ct - tl) * HH;
        for (size_t i = 4 * (size_t)tid; i < total; i += 4 * NT)
            *reinterpret_cast<float4*>(y + base + i) = z;
    }

    // persist state for next chunk
    if (actlane) {
        *reinterpret_cast<float2*>(cst + b * HH + 2 * p) = c01;
        u32 hu = hbuf[pp][p];
        __half2 hp = *reinterpret_cast<__half2*>(&hu);
        float2 hf = __half22float2(hp);
        *reinterpret_cast<float2*>(hst + b * HH + 2 * p) = hf;
    }
}

// ---------------- host ----------------
extern "C" void kernel_launch(void* const* d_in, const int* in_sizes, int n_in,
                              void* d_out, int out_size, void* d_ws, size_t ws_size,
                              hipStream_t stream) {
    (void)in_sizes; (void)n_in; (void)out_size;
    const float* x      = (const float*)d_in[0];
    const float* W      = (const float*)d_in[1];
    const float* bias   = (const float*)d_in[2];
    const int*   seqlen = (const int*)d_in[3];
    float* y = (float*)d_out;

    // workspace layout: [whp 512KB][c 64KB][h 64KB][xw chunk buffer ...]
    u32*   whp = (u32*)d_ws;
    float* cst = (float*)((char*)d_ws + (512 << 10));
    float* hst = cst + BB * HH;
    float* xwbuf = (float*)((char*)d_ws + (640 << 10));

    long long avail = (long long)ws_size - (640 << 10);
    int ctu = 128;
    if (avail > 0) {
        long long mx = avail / ((long long)BB * G4 * 4);  // 256KB per timestep
        int mm = (int)((mx / 128) * 128);
        if (mm >= 128) ctu = mm;
    }
    if (ctu > TT) ctu = TT;

    prep_wh<<<dim3(512), 256, 0, stream>>>(W, whp);
    init_state<<<dim3(64), 256, 0, stream>>>(cst, hst);

    int done = 0;
    while (done < TT) {
        int ct = ctu;
        if (ct > TT - done) ct = TT - done;
        gemm_xw<<<dim3((BB * ct) / BM, G4 / BN), 256, 0, stream>>>(x, W, bias, seqlen, xwbuf, done, ct);
        lstm_chunk<<<dim3(BB), NT, 0, stream>>>(whp, xwbuf, seqlen, y, cst, hst, done, ct);
        done += ct;
    }
}